// Round 6
// baseline (209.933 us; speedup 1.0000x reference)
//
#include <hip/hip_runtime.h>
#include <hip/hip_bf16.h>

typedef unsigned short ushort_t;
typedef unsigned int uint32;
typedef __attribute__((ext_vector_type(8))) short short8;
typedef __attribute__((ext_vector_type(4))) short short4_t;
typedef __attribute__((ext_vector_type(4))) float f32x4;

// Problem constants: B=2, S=2048, D=1024, H=16, DK=64
#define NB 2
#define NS 2048
#define ND 1024
#define NH 16

__device__ __forceinline__ float bf2f(ushort_t u) {
  return __uint_as_float(((uint32)u) << 16);
}
__device__ __forceinline__ ushort_t f2bf(float x) {
  uint32 u = __float_as_uint(x);
  uint32 r = u + 0x7FFFu + ((u >> 16) & 1u);  // RNE
  return (ushort_t)(r >> 16);
}

__device__ __forceinline__ void gload16(const void* g, void* l) {
  __builtin_amdgcn_global_load_lds(
      (const __attribute__((address_space(1))) void*)g,
      (__attribute__((address_space(3))) void*)l, 16, 0, 0);
}

// ---------------------------------------------------------------------------
// fp32 -> bf16 convert for WEIGHTS only (wq,wk,wv,wo): 4 x 512 blocks.
// ---------------------------------------------------------------------------
__global__ __launch_bounds__(256) void convert_w_kernel(
    const float* wq, const float* wk, const float* wv, const float* wo,
    ushort_t* Wq, ushort_t* Wk, ushort_t* Wv, ushort_t* Wo) {
  const int blk = blockIdx.x;
  const float* src;
  ushort_t* dst;
  int base;
  if (blk < 512) { src = wq; dst = Wq; base = blk; }
  else if (blk < 1024) { src = wk; dst = Wk; base = blk - 512; }
  else if (blk < 1536) { src = wv; dst = Wv; base = blk - 1024; }
  else { src = wo; dst = Wo; base = blk - 1536; }
  const size_t off = (size_t)base * 2048 + (size_t)threadIdx.x * 8;
  const float4 v0 = *(const float4*)&src[off];
  const float4 v1 = *(const float4*)&src[off + 4];
  short8 o;
  o[0] = (short)f2bf(v0.x); o[1] = (short)f2bf(v0.y);
  o[2] = (short)f2bf(v0.z); o[3] = (short)f2bf(v0.w);
  o[4] = (short)f2bf(v1.x); o[5] = (short)f2bf(v1.y);
  o[6] = (short)f2bf(v1.z); o[7] = (short)f2bf(v1.w);
  *(short8*)&dst[off] = o;
}

// ---------------------------------------------------------------------------
// proj GEMM, fused fp32->bf16 on A: Y[128,128] = A_f32[.,1024] @ Bt_bf16^T + b
// Double-buffered LDS, ONE barrier per K-step (T3 minimum-2-phase):
//   iter t: {ds_write A(t+1) from regs; gload_lds B(t+1); issue A-loads(t+2)}
//           then ds_read+MFMA tile t; __syncthreads.
// Staging latency hides under compute instead of draining at issue.
// 256 thr = 4 waves 2x2; wave tile 64x64 = 4x4 mfma_f32_16x16x32_bf16; BK=32.
// ---------------------------------------------------------------------------
__device__ __forceinline__ void gemm128x128_f32A(
    const float* __restrict__ A, const ushort_t* __restrict__ Bt,
    const float* __restrict__ bias, ushort_t* __restrict__ Y, int bm, int bn) {
  constexpr int K = 1024;
  constexpr int NT = K / 32;
  constexpr int NY = 1024;
  __shared__ __align__(16) ushort_t sA[2 * 128 * 32];
  __shared__ __align__(16) ushort_t sB[2 * 128 * 32];
  const int t = threadIdx.x;
  const int lane = t & 63;
  const int w = t >> 6;
  const int wr = w >> 1, wc = w & 1;
  const int r15 = lane & 15, kh = lane >> 4;
  const int m0 = bm * 128, n0 = bn * 128;

  f32x4 acc[4][4] = {};

  // A staging map: f4idx = t + i*256 -> row = (t>>3)+i*32, c4 = t&7
  const int rowA = t >> 3, c4 = t & 7;
  const float* gA = A + (size_t)(m0 + rowA) * K + c4 * 4;
  // B staging map: chunk c in 0..511: row = c>>2, col8 = (c&3)*8
  const int rowB = t >> 2, cc8 = (t & 3) * 8;
  const ushort_t* gB0 = Bt + (size_t)(n0 + rowB) * K + cc8;
  const ushort_t* gB1 = Bt + (size_t)(n0 + rowB + 64) * K + cc8;

  float4 ar[4];
#define LOADA(tile)                                                        \
  {                                                                        \
    const int k0_ = (tile) * 32;                                           \
    _Pragma("unroll") for (int i = 0; i < 4; ++i) ar[i] =                  \
        *(const float4*)&gA[(size_t)(i * 32) * K + k0_];                   \
  }
#define WRITEA(bufsel)                                                     \
  {                                                                        \
    ushort_t* sAw_ = &sA[(bufsel) * 4096];                                 \
    _Pragma("unroll") for (int i = 0; i < 4; ++i) {                        \
      short4_t s_;                                                         \
      s_[0] = (short)f2bf(ar[i].x);                                        \
      s_[1] = (short)f2bf(ar[i].y);                                        \
      s_[2] = (short)f2bf(ar[i].z);                                        \
      s_[3] = (short)f2bf(ar[i].w);                                        \
      *(short4_t*)&sAw_[(rowA + i * 32) * 32 + c4 * 4] = s_;               \
    }                                                                      \
  }
#define STAGEB(tile, bufsel)                                               \
  {                                                                        \
    ushort_t* sBw_ = &sB[(bufsel) * 4096];                                 \
    gload16(gB0 + (tile) * 32, &sBw_[t * 8]);                              \
    gload16(gB1 + (tile) * 32, &sBw_[(t + 256) * 8]);                      \
  }

  // prologue: tile 0 into buf 0; preload A(1) into regs
  LOADA(0);
  STAGEB(0, 0);
  WRITEA(0);  // compiler inserts vmcnt wait on ar
  LOADA(1);
  __syncthreads();

  int cur = 0;
  for (int tt = 0; tt < NT; ++tt) {
    if (tt + 1 < NT) {
      WRITEA(cur ^ 1);       // tile tt+1 (regs loaded last iter)
      STAGEB(tt + 1, cur ^ 1);
      if (tt + 2 < NT) LOADA(tt + 2);
    }
    const ushort_t* sAc = &sA[cur * 4096];
    const ushort_t* sBc = &sB[cur * 4096];
    short8 af[4], bfr[4];
#pragma unroll
    for (int m = 0; m < 4; ++m)
      af[m] = *(const short8*)&sAc[(wr * 64 + m * 16 + r15) * 32 + kh * 8];
#pragma unroll
    for (int n = 0; n < 4; ++n)
      bfr[n] = *(const short8*)&sBc[(wc * 64 + n * 16 + r15) * 32 + kh * 8];
#pragma unroll
    for (int m = 0; m < 4; ++m)
#pragma unroll
      for (int n = 0; n < 4; ++n)
        acc[m][n] = __builtin_amdgcn_mfma_f32_16x16x32_bf16(af[m], bfr[n],
                                                            acc[m][n], 0, 0, 0);
    __syncthreads();  // staging of cur^1 complete; readers of cur done
    cur ^= 1;
  }
#undef LOADA
#undef WRITEA
#undef STAGEB

  const int orow0 = m0 + wr * 64 + kh * 4;
  const int ocol0 = n0 + wc * 64 + r15;
#pragma unroll
  for (int m = 0; m < 4; ++m) {
#pragma unroll
    for (int n = 0; n < 4; ++n) {
      const int col = ocol0 + n * 16;
      const float bv = bias[col];
#pragma unroll
      for (int j = 0; j < 4; ++j) {
        const int row = orow0 + m * 16 + j;
        Y[(size_t)row * NY + col] = f2bf(acc[m][n][j] + bv);
      }
    }
  }
}

// ---------------------------------------------------------------------------
// out GEMM 64x128, all-bf16 inputs via gload_lds, double-buffered 1-barrier.
// ---------------------------------------------------------------------------
__device__ __forceinline__ void gemm64x128_dbuf(
    const ushort_t* __restrict__ A, const ushort_t* __restrict__ Bt,
    const float* __restrict__ bias, float* __restrict__ Y, int bm, int bn) {
  constexpr int K = 1024;
  constexpr int NT = K / 32;
  constexpr int NY = 1024;
  __shared__ __align__(16) ushort_t sA[2 * 64 * 32];
  __shared__ __align__(16) ushort_t sB[2 * 128 * 32];
  const int t = threadIdx.x;
  const int lane = t & 63;
  const int w = t >> 6;
  const int wr = w >> 1, wc = w & 1;
  const int r15 = lane & 15, kh = lane >> 4;
  const int m0 = bm * 64, n0 = bn * 128;

  f32x4 acc[2][4] = {};

  const int rowX = t >> 2, cc8 = (t & 3) * 8;
  const ushort_t* gA = A + (size_t)(m0 + rowX) * K + cc8;
  const ushort_t* gB0 = Bt + (size_t)(n0 + rowX) * K + cc8;
  const ushort_t* gB1 = Bt + (size_t)(n0 + rowX + 64) * K + cc8;

#define STAGE(tile, bufsel)                                                \
  {                                                                        \
    const int k0_ = (tile) * 32;                                           \
    gload16(gA + k0_, &sA[(bufsel) * 2048 + t * 8]);                       \
    gload16(gB0 + k0_, &sB[(bufsel) * 4096 + t * 8]);                      \
    gload16(gB1 + k0_, &sB[(bufsel) * 4096 + (t + 256) * 8]);              \
  }

  STAGE(0, 0);
  __syncthreads();

  int cur = 0;
  for (int tt = 0; tt < NT; ++tt) {
    if (tt + 1 < NT) STAGE(tt + 1, cur ^ 1);
    const ushort_t* sAc = &sA[cur * 2048];
    const ushort_t* sBc = &sB[cur * 4096];
    short8 af[2], bfr[4];
#pragma unroll
    for (int m = 0; m < 2; ++m)
      af[m] = *(const short8*)&sAc[(wr * 32 + m * 16 + r15) * 32 + kh * 8];
#pragma unroll
    for (int n = 0; n < 4; ++n)
      bfr[n] = *(const short8*)&sBc[(wc * 64 + n * 16 + r15) * 32 + kh * 8];
#pragma unroll
    for (int m = 0; m < 2; ++m)
#pragma unroll
      for (int n = 0; n < 4; ++n)
        acc[m][n] = __builtin_amdgcn_mfma_f32_16x16x32_bf16(af[m], bfr[n],
                                                            acc[m][n], 0, 0, 0);
    __syncthreads();
    cur ^= 1;
  }
#undef STAGE

  const int orow0 = m0 + wr * 32 + kh * 4;
  const int ocol0 = n0 + wc * 64 + r15;
#pragma unroll
  for (int m = 0; m < 2; ++m) {
#pragma unroll
    for (int n = 0; n < 4; ++n) {
      const int col = ocol0 + n * 16;
      const float bv = bias[col];
#pragma unroll
      for (int j = 0; j < 4; ++j) {
        const int row = orow0 + m * 16 + j;
        Y[(size_t)row * NY + col] = acc[m][n][j] + bv;
      }
    }
  }
}

// Fused Q/K/V projections from RAW fp32 inputs: grid 3*256, T1 XCD-chunked.
__global__ __launch_bounds__(256) void proj_qkv_kernel(
    const float* q, const float* k, const float* v,
    const ushort_t* Wq, const ushort_t* Wk, const ushort_t* Wv,
    const float* bq, const float* bk, const float* bv,
    ushort_t* Qb, ushort_t* Kb, ushort_t* Vb) {
  const int blk = blockIdx.x;
  const int tsel = blk >> 8;
  int rem = blk & 255;
  rem = (rem & 7) * 32 + (rem >> 3);  // XCD-chunked (256 % 8 == 0, bijective)
  const int bm = rem >> 3, bn = rem & 7;
  const float* A = tsel == 0 ? q : (tsel == 1 ? k : v);
  const ushort_t* Bt = tsel == 0 ? Wq : (tsel == 1 ? Wk : Wv);
  const float* bias = tsel == 0 ? bq : (tsel == 1 ? bk : bv);
  ushort_t* Y = tsel == 0 ? Qb : (tsel == 1 ? Kb : Vb);
  gemm128x128_f32A(A, Bt, bias, Y, bm, bn);
}

// Final: out = Q @ Ct[batch]^T + b_o (fp32). grid 512, XCD-chunked.
__global__ __launch_bounds__(256) void out_gemm_kernel(
    const ushort_t* Qb, const ushort_t* Ct, const float* bo, float* out) {
  int blk = blockIdx.x;  // 0..511
  blk = (blk & 7) * 64 + (blk >> 3);  // XCD-chunked (512 % 8 == 0)
  const int bm = blk >> 3, bn = blk & 7;
  const ushort_t* Bt = Ct + (size_t)(bm >> 5) * 1024 * 1024;
  gemm64x128_dbuf(Qb, Bt, bo, out, bm, bn);
}

// ---------------------------------------------------------------------------
// Mpart[bh][c][d1*64+d2] = sum_{s in chunk c} K[b,s,h*64+d1] * V[b,s,h*64+d2]
// ---------------------------------------------------------------------------
__global__ __launch_bounds__(256) void kv_outer_kernel(
    const ushort_t* __restrict__ Kb, const ushort_t* __restrict__ Vb,
    float* __restrict__ Mpart) {
  const int bh = blockIdx.x >> 4;
  const int c = blockIdx.x & 15;
  const int b = bh >> 4, h = bh & 15;
  __shared__ __align__(16) ushort_t sK[128][64];
  __shared__ __align__(16) ushort_t sV[128][64];
  const int t = threadIdx.x;
  const ushort_t* baseK = Kb + (size_t)(b * NS + c * 128) * ND + h * 64;
  const ushort_t* baseV = Vb + (size_t)(b * NS + c * 128) * ND + h * 64;
#pragma unroll
  for (int i = 0; i < 4; ++i) {
    const int ch = t + i * 256;
    const int row = ch >> 3, cc = ch & 7;
    *(short8*)&sK[row][cc * 8] = *(const short8*)&baseK[(size_t)row * ND + cc * 8];
    *(short8*)&sV[row][cc * 8] = *(const short8*)&baseV[(size_t)row * ND + cc * 8];
  }
  __syncthreads();
  const int d1 = (t & 15) * 4, d2 = (t >> 4) * 4;
  float acc[4][4] = {};
  for (int s = 0; s < 128; ++s) {
    const uint2 ku = *(const uint2*)&sK[s][d1];
    const uint2 vu = *(const uint2*)&sV[s][d2];
    float kx[4], vx[4];
    kx[0] = __uint_as_float(ku.x << 16);
    kx[1] = __uint_as_float(ku.x & 0xFFFF0000u);
    kx[2] = __uint_as_float(ku.y << 16);
    kx[3] = __uint_as_float(ku.y & 0xFFFF0000u);
    vx[0] = __uint_as_float(vu.x << 16);
    vx[1] = __uint_as_float(vu.x & 0xFFFF0000u);
    vx[2] = __uint_as_float(vu.y << 16);
    vx[3] = __uint_as_float(vu.y & 0xFFFF0000u);
#pragma unroll
    for (int a2 = 0; a2 < 4; ++a2)
#pragma unroll
      for (int b2 = 0; b2 < 4; ++b2) acc[a2][b2] += kx[a2] * vx[b2];
  }
  float* outp = Mpart + ((size_t)bh * 16 + c) * 4096;
#pragma unroll
  for (int a2 = 0; a2 < 4; ++a2)
#pragma unroll
    for (int b2 = 0; b2 < 4; ++b2)
      outp[(d1 + a2) * 64 + (d2 + b2)] = acc[a2][b2];
}

// Mred[bh][e] = (1/8) * sum_c Mpart[bh][c][e]
__global__ __launch_bounds__(256) void reduce_M_kernel(
    const float* __restrict__ Mpart, float* __restrict__ Mred) {
  const int idx = blockIdx.x * 256 + threadIdx.x;
  const int bh = idx >> 12, e = idx & 4095;
  float s = 0.f;
#pragma unroll
  for (int c = 0; c < 16; ++c) s += Mpart[((size_t)bh * 16 + c) * 4096 + e];
  Mred[idx] = s * 0.125f;
}

// ---------------------------------------------------------------------------
// Ct[b][j][k] = sum_i M[b,h(k)][k&63][i] * w_o[j][h(k)*64+i]
// ---------------------------------------------------------------------------
__global__ __launch_bounds__(256) void build_C_kernel(
    const float* __restrict__ Mred, const ushort_t* __restrict__ Wo,
    ushort_t* __restrict__ Ct) {
  const int blk = blockIdx.x;
  const int b = blk >> 8, h = (blk >> 4) & 15, jb = blk & 15;
  __shared__ float sM[64][65];
  __shared__ __align__(16) ushort_t sW[64][72];
  const int t = threadIdx.x;
  const float* Mp = Mred + (size_t)(b * 16 + h) * 4096;
#pragma unroll
  for (int i = 0; i < 16; ++i) {
    const int e = t + i * 256;
    sM[e >> 6][e & 63] = Mp[e];
  }
  const int j0 = jb * 64;
#pragma unroll
  for (int i = 0; i < 2; ++i) {
    const int ch = t + i * 256;
    const int row = ch >> 3, cc = ch & 7;
    *(short8*)&sW[row][cc * 8] =
        *(const short8*)&Wo[(size_t)(j0 + row) * ND + h * 64 + cc * 8];
  }
  __syncthreads();
  const int kk = (t & 15) * 4, jj = (t >> 4) * 4;
  float acc[4][4] = {};
  for (int i = 0; i < 64; ++i) {
    float mv[4], wv[4];
#pragma unroll
    for (int a2 = 0; a2 < 4; ++a2) mv[a2] = sM[kk + a2][i];
#pragma unroll
    for (int b2 = 0; b2 < 4; ++b2) wv[b2] = bf2f(sW[jj + b2][i]);
#pragma unroll
    for (int a2 = 0; a2 < 4; ++a2)
#pragma unroll
      for (int b2 = 0; b2 < 4; ++b2) acc[a2][b2] += mv[a2] * wv[b2];
  }
#pragma unroll
  for (int a2 = 0; a2 < 4; ++a2)
#pragma unroll
    for (int b2 = 0; b2 < 4; ++b2)
      Ct[((size_t)b * ND + j0 + jj + b2) * ND + h * 64 + kk + a2] =
          f2bf(acc[a2][b2]);
}

// ---------------------------------------------------------------------------
extern "C" void kernel_launch(void* const* d_in, const int* in_sizes, int n_in,
                              void* d_out, int out_size, void* d_ws,
                              size_t ws_size, hipStream_t stream) {
  (void)in_sizes; (void)n_in; (void)out_size; (void)ws_size;
  const float* q = (const float*)d_in[0];
  const float* k = (const float*)d_in[1];
  const float* v = (const float*)d_in[2];
  const float* wq = (const float*)d_in[3];
  const float* bq = (const float*)d_in[4];
  const float* wk = (const float*)d_in[5];
  const float* bk = (const float*)d_in[6];
  const float* wv = (const float*)d_in[7];
  const float* bv = (const float*)d_in[8];
  const float* wo = (const float*)d_in[9];
  const float* bo = (const float*)d_in[10];
  float* out = (float*)d_out;

  const size_t MB = 1048576;
  char* ws = (char*)d_ws;
  ushort_t* Wq = (ushort_t*)(ws + 0 * MB);    // 2 MB [1024,1024] bf16
  ushort_t* Wk = (ushort_t*)(ws + 2 * MB);    // 2 MB
  ushort_t* Wv = (ushort_t*)(ws + 4 * MB);    // 2 MB
  ushort_t* Wo = (ushort_t*)(ws + 6 * MB);    // 2 MB
  ushort_t* Qb = (ushort_t*)(ws + 8 * MB);    // 8 MB [4096,1024] bf16
  ushort_t* Kb = (ushort_t*)(ws + 16 * MB);   // 8 MB
  ushort_t* Vb = (ushort_t*)(ws + 24 * MB);   // 8 MB
  float* Mpart = (float*)(ws + 32 * MB);      // 8 MB [32][16][4096] f32
  float* Mred = (float*)(ws + 40 * MB);       // 512 KB [32][4096] f32
  ushort_t* Ct = (ushort_t*)(ws + 40 * MB + 524288);  // 4 MB

  hipLaunchKernelGGL(convert_w_kernel, dim3(2048), dim3(256), 0, stream, wq, wk,
                     wv, wo, Wq, Wk, Wv, Wo);
  hipLaunchKernelGGL(proj_qkv_kernel, dim3(768), dim3(256), 0, stream, q, k, v,
                     Wq, Wk, Wv, bq, bk, bv, Qb, Kb, Vb);
  hipLaunchKernelGGL(kv_outer_kernel, dim3(512), dim3(256), 0, stream, Kb, Vb,
                     Mpart);
  hipLaunchKernelGGL(reduce_M_kernel, dim3(512), dim3(256), 0, stream, Mpart,
                     Mred);
  hipLaunchKernelGGL(build_C_kernel, dim3(512), dim3(256), 0, stream, Mred, Wo,
                     Ct);
  hipLaunchKernelGGL(out_gemm_kernel, dim3(512), dim3(256), 0, stream, Qb, Ct,
                     bo, out);
}